// Round 5
// baseline (484.579 us; speedup 1.0000x reference)
//
#include <hip/hip_runtime.h>
#include <math.h>

typedef unsigned short u16x8 __attribute__((ext_vector_type(8)));
typedef short s16x8 __attribute__((ext_vector_type(8)));
typedef float f32x4 __attribute__((ext_vector_type(4)));

__device__ __forceinline__ float bf2f(unsigned short u) {
    union { unsigned int i; float f; } v; v.i = ((unsigned int)u) << 16; return v.f;
}
__device__ __forceinline__ unsigned short f2bf(float f) {
    union { unsigned int i; float f; } v; v.f = f;
    unsigned int r = v.i + 0x7FFFu + ((v.i >> 16) & 1u);
    return (unsigned short)(r >> 16);
}

// ---------------- workspace layout (bytes) ----------------
// w32 f32:   [0, 16384)
// MATS bf16: [16384, 548864)     128h x 2080: V[32][32] | G[32][32] | kker[32]
// WB bf16:   [548864, 942080)    4 x 128co x 384k
// stats f32: [942080, 946176)    raw sums {s1,s2} per (branch,co)
// y/z bf16:  [1048576, +33554432)
// yT bf16:   [34603008, +33554432)
#define MATS_OFF 16384
#define WB_OFF   548864
#define STAT_OFF 942080
#define Y_OFF    1048576
#define YT_OFF   34603008
#define Z_OFF    Y_OFF

// ============ kernel 1: S4D matrix precompute (double precision) ============
__global__ void precompute_s4d(const float* __restrict__ log_dt,
                               const float* __restrict__ A_log,
                               const float* __restrict__ A_imag,
                               const float* __restrict__ B_re,
                               const float* __restrict__ B_im,
                               const float* __restrict__ C_re,
                               const float* __restrict__ C_im,
                               float* __restrict__ w32,
                               unsigned short* __restrict__ MATS)
{
    const int h = blockIdx.x;
    const int tid = threadIdx.x;
    const double dt = exp((double)log_dt[h]);

    // V entries
    #pragma unroll 1
    for (int it = 0; it < 4; it++) {
        int idx = tid + (it << 8);
        int s = idx >> 5, i = idx & 31;
        int n = s >> 1;
        double Ar = -exp((double)A_log[h * 16 + n]);
        double Ai = (double)A_imag[h * 16 + n];
        double dr = dt * Ar, di = dt * Ai;
        double l = (double)(31 - i);
        double e = exp(l * dr);
        double val = (s & 1) ? e * sin(l * di) : e * cos(l * di);
        MATS[(size_t)h * 2080 + s * 32 + i] = f2bf((float)val);
    }
    // G entries
    #pragma unroll 1
    for (int it = 0; it < 4; it++) {
        int idx = tid + (it << 8);
        int j = idx >> 5, s = idx & 31;
        int n = s >> 1;
        double Ar = -exp((double)A_log[h * 16 + n]);
        double Ai = (double)A_imag[h * 16 + n];
        double dr = dt * Ar, di = dt * Ai;
        double ew = exp(dr);
        double wr = ew * cos(di), wi = ew * sin(di);
        double nr = wr - 1.0, ni = wi;
        double inv = 1.0 / (Ar * Ar + Ai * Ai);
        double tr = (nr * Ar + ni * Ai) * inv;
        double ti = (ni * Ar - nr * Ai) * inv;
        double Br = (double)B_re[h * 16 + n], Bi = (double)B_im[h * 16 + n];
        double dbr = tr * Br - ti * Bi, dbi = tr * Bi + ti * Br;
        double Cr = (double)C_re[h * 16 + n], Ci = (double)C_im[h * 16 + n];
        double cbr = Cr * dbr - Ci * dbi, cbi = Cr * dbi + Ci * dbr;
        double m = (double)(j + 1);
        double e = exp(m * dr);
        double pr = e * cos(m * di), pi = e * sin(m * di);
        double gr = cbr * pr - cbi * pi, gi = cbr * pi + cbi * pr;
        double val = (s & 1) ? -2.0 * gi : 2.0 * gr;
        MATS[(size_t)h * 2080 + 1024 + j * 32 + s] = f2bf((float)val);
    }
    // kker spread over all 256 threads: l = tid>>3, each sub-thread sums 2 n's
    {
        int l = tid >> 3, sub = tid & 7;
        double accd = 0.0;
        #pragma unroll 1
        for (int q = 0; q < 2; q++) {
            int n = sub * 2 + q;
            double Ar = -exp((double)A_log[h * 16 + n]);
            double Ai = (double)A_imag[h * 16 + n];
            double dr = dt * Ar, di = dt * Ai;
            double ew = exp(dr);
            double wr = ew * cos(di), wi = ew * sin(di);
            double nr = wr - 1.0, ni = wi;
            double inv = 1.0 / (Ar * Ar + Ai * Ai);
            double tr = (nr * Ar + ni * Ai) * inv;
            double ti = (ni * Ar - nr * Ai) * inv;
            double Br = (double)B_re[h * 16 + n], Bi = (double)B_im[h * 16 + n];
            double dbr = tr * Br - ti * Bi, dbi = tr * Bi + ti * Br;
            double Cr = (double)C_re[h * 16 + n], Ci = (double)C_im[h * 16 + n];
            double cbr = Cr * dbr - Ci * dbi, cbi = Cr * dbi + Ci * dbr;
            double l2 = (double)l;
            double e = exp(l2 * dr);
            double wlr = e * cos(l2 * di), wli = e * sin(l2 * di);
            accd += cbr * wlr - cbi * wli;
        }
        float accf = (float)(2.0 * accd);
        #pragma unroll
        for (int o = 4; o > 0; o >>= 1) accf += __shfl_down(accf, o, 8);
        if (sub == 0) MATS[(size_t)h * 2080 + 2048 + l] = f2bf(accf);
    }
    // w32
    if (tid < 16) {
        int n = tid;
        double Ar = -exp((double)A_log[h * 16 + n]);
        double Ai = (double)A_imag[h * 16 + n];
        double dr = dt * Ar, di = dt * Ai;
        double e = exp(32.0 * dr);
        w32[h * 32 + 2 * n]     = (float)(e * cos(32.0 * di));
        w32[h * 32 + 2 * n + 1] = (float)(e * sin(32.0 * di));
    }
}

// ============ kernel 1b: pack conv weights to bf16 ============
__global__ void wpack(const float* __restrict__ w1, const float* __restrict__ w2,
                      const float* __restrict__ w3, const float* __restrict__ w4,
                      unsigned short* __restrict__ WB)
{
    int idx = blockIdx.x * 256 + threadIdx.x;
    int br = idx / 49152;
    int r  = idx - br * 49152;
    int co = r / 384;
    int k  = r - co * 384;
    int tap = k >> 7, h = k & 127;
    const float* wp = (br == 0) ? w1 : (br == 1) ? w2 : (br == 2) ? w3 : w4;
    WB[idx] = f2bf(wp[co * 384 + h * 3 + tap]);
}

// ============ kernel 1c: zero BN stat sums ============
__global__ void stats_zero(float* __restrict__ stats)
{
    int i = threadIdx.x;
    #pragma unroll
    for (int k = 0; k < 4; k++) stats[i + k * 256] = 0.f;
}

// ============ kernel 2: S4D — MFMA chunk matmuls + shuffle carry scan ============
__global__ __launch_bounds__(256, 2) void s4d_mfma(const float* __restrict__ x,
                                                   const float* __restrict__ w32,
                                                   const unsigned short* __restrict__ MATS,
                                                   const float* __restrict__ Dp,
                                                   unsigned short* __restrict__ yout)
{
    __shared__ unsigned short sXc[256 * 40];
    __shared__ unsigned short sM[3840];        // V @0, TK @1280, G @2560 (stride 40)
    __shared__ float spow2[256];               // w32^(2^k), k=0..7
    __shared__ unsigned short skr[32];
    __shared__ float swc[128];                 // cross-wave carries 4x32
    __shared__ float scratch[8320];            // 32 x 260 unpack buffer / sCc u16
    const int tid = threadIdx.x;
    const int bh = blockIdx.x;
    const int h = bh & 127;
    const int lane = tid & 63, w = tid >> 6;
    const int ml = lane & 15, kg = lane >> 4;

    // ---- x chunk -> registers + sXc (bf16) ----
    float xr[32];
    const float4* xp4 = (const float4*)(x + ((size_t)bh << 13) + (tid << 5));
    #pragma unroll
    for (int i = 0; i < 8; i++) {
        float4 v = xp4[i];
        xr[4 * i] = v.x; xr[4 * i + 1] = v.y; xr[4 * i + 2] = v.z; xr[4 * i + 3] = v.w;
    }
    #pragma unroll
    for (int g = 0; g < 4; g++) {
        u16x8 pk;
        #pragma unroll
        for (int e = 0; e < 8; e++) pk[e] = f2bf(xr[g * 8 + e]);
        *(u16x8*)&sXc[tid * 40 + g * 8] = pk;
    }
    // ---- stage V, G ----
    {
        int matv = tid >> 7, r = (tid >> 2) & 31, sg = tid & 3;
        u16x8 v = *(const u16x8*)(MATS + (size_t)h * 2080 + matv * 1024 + r * 32 + sg * 8);
        *(u16x8*)&sM[matv * 2560 + r * 40 + sg * 8] = v;
    }
    if (tid < 4) {
        u16x8 v = *(const u16x8*)(MATS + (size_t)h * 2080 + 2048 + tid * 8);
        *(u16x8*)&skr[tid * 8] = v;
    }
    if (tid < 16) {
        float rr = w32[h * 32 + 2 * tid], ii = w32[h * 32 + 2 * tid + 1];
        #pragma unroll
        for (int k = 0; k < 8; k++) {
            spow2[k * 32 + 2 * tid] = rr; spow2[k * 32 + 2 * tid + 1] = ii;
            float n2r = rr * rr - ii * ii, n2i = 2.f * rr * ii;
            rr = n2r; ii = n2i;
        }
    }
    __syncthreads();
    // ---- expand Toeplitz TK from kker ----
    #pragma unroll
    for (int it = 0; it < 4; it++) {
        int idx = tid + (it << 8);
        int j = idx >> 5, i = idx & 31;
        sM[1280 + j * 40 + i] = (i <= j) ? skr[j - i] : (unsigned short)0;
    }
    __syncthreads();

    // ---- E = V @ Xc (chunk end-states) ----
    f32x4 acc[2][4];
    #pragma unroll
    for (int mt = 0; mt < 2; mt++)
        #pragma unroll
        for (int nt = 0; nt < 4; nt++) acc[mt][nt] = (f32x4)(0.f);
    {
        s16x8 af[2], bfr[4];
        #pragma unroll
        for (int mt = 0; mt < 2; mt++)
            af[mt] = *(const s16x8*)&sM[(mt * 16 + ml) * 40 + kg * 8];
        #pragma unroll
        for (int nt = 0; nt < 4; nt++)
            bfr[nt] = *(const s16x8*)&sXc[(w * 64 + nt * 16 + ml) * 40 + kg * 8];
        #pragma unroll
        for (int mt = 0; mt < 2; mt++)
            #pragma unroll
            for (int nt = 0; nt < 4; nt++)
                acc[mt][nt] = __builtin_amdgcn_mfma_f32_16x16x32_bf16(af[mt], bfr[nt], acc[mt][nt], 0, 0, 0);
    }
    #pragma unroll
    for (int mt = 0; mt < 2; mt++)
        #pragma unroll
        for (int nt = 0; nt < 4; nt++)
            #pragma unroll
            for (int r = 0; r < 4; r++)
                scratch[(mt * 16 + kg * 4 + r) * 260 + (w * 64 + nt * 16 + ml)] = acc[mt][nt][r];
    __syncthreads();
    float zr[16], zi[16];
    #pragma unroll
    for (int n = 0; n < 16; n++) {
        zr[n] = scratch[(2 * n) * 260 + tid];
        zi[n] = scratch[(2 * n + 1) * 260 + tid];
    }

    // ---- in-wave inclusive scan over 64 chunks (shuffles, no barriers) ----
    #pragma unroll 1
    for (int k = 0; k < 6; k++) {
        const int o = 1 << k;
        const bool act = lane >= o;
        #pragma unroll
        for (int n = 0; n < 16; n++) {
            float lr = __shfl(zr[n], lane - o);
            float li = __shfl(zi[n], lane - o);
            float mr = spow2[(k << 5) + 2 * n], mi = spow2[(k << 5) + 2 * n + 1];
            float nzr = fmaf(mr, lr, fmaf(-mi, li, zr[n]));
            float nzi = fmaf(mr, li, fmaf(mi, lr, zi[n]));
            zr[n] = act ? nzr : zr[n];
            zi[n] = act ? nzi : zi[n];
        }
    }
    // ---- cross-wave carries ----
    if (lane == 63) {
        #pragma unroll
        for (int n = 0; n < 16; n++) {
            swc[w * 32 + 2 * n]     = zr[n];
            swc[w * 32 + 2 * n + 1] = zi[n];
        }
    }
    __syncthreads();   // also guarantees all E-reads from scratch are done
    float qr[16], qi[16];
    #pragma unroll
    for (int n = 0; n < 16; n++) { qr[n] = 0.f; qi[n] = 0.f; }
    #pragma unroll 1
    for (int a = 0; a < 3; a++) {
        if (a < w) {
            int p = w - 1 - a;   // 0: id, 1: w32^64 (k=6), 2: w32^128 (k=7)
            #pragma unroll
            for (int n = 0; n < 16; n++) {
                float ar = swc[a * 32 + 2 * n], ai = swc[a * 32 + 2 * n + 1];
                float mr = 1.f, mi = 0.f;
                if (p > 0) { mr = spow2[((5 + p) << 5) + 2 * n]; mi = spow2[((5 + p) << 5) + 2 * n + 1]; }
                qr[n] = fmaf(mr, ar, fmaf(-mi, ai, qr[n]));
                qi[n] = fmaf(mr, ai, fmaf(mi, ar, qi[n]));
            }
        }
    }
    // ---- per-lane w32^lane by binary powering ----
    float pjr[16], pji[16];
    #pragma unroll
    for (int n = 0; n < 16; n++) { pjr[n] = 1.f; pji[n] = 0.f; }
    #pragma unroll 1
    for (int k = 0; k < 6; k++) {
        const bool bit = (lane >> k) & 1;
        #pragma unroll
        for (int n = 0; n < 16; n++) {
            float mr = spow2[(k << 5) + 2 * n], mi = spow2[(k << 5) + 2 * n + 1];
            float nr2 = pjr[n] * mr - pji[n] * mi;
            float ni2 = fmaf(pjr[n], mi, pji[n] * mr);
            pjr[n] = bit ? nr2 : pjr[n];
            pji[n] = bit ? ni2 : pji[n];
        }
    }
    // ---- exclusive carry per chunk: X = P_{lane-1} + w32^lane * Q_w ----
    #pragma unroll
    for (int n = 0; n < 16; n++) {
        float pr = __shfl(zr[n], lane - 1);
        float pi = __shfl(zi[n], lane - 1);
        pr = (lane == 0) ? 0.f : pr;
        pi = (lane == 0) ? 0.f : pi;
        zr[n] = fmaf(pjr[n], qr[n], fmaf(-pji[n], qi[n], pr));
        zi[n] = fmaf(pjr[n], qi[n], fmaf(pji[n], qr[n], pi));
    }
    // ---- write carries as bf16 rows: sCc[chunk][s] (into scratch) ----
    {
        unsigned short* sCc = (unsigned short*)scratch;
        #pragma unroll
        for (int g = 0; g < 4; g++) {
            u16x8 pk;
            #pragma unroll
            for (int q = 0; q < 4; q++) {
                pk[2 * q]     = f2bf(zr[g * 4 + q]);
                pk[2 * q + 1] = f2bf(zi[g * 4 + q]);
            }
            *(u16x8*)&sCc[tid * 40 + g * 8] = pk;
        }
    }
    __syncthreads();

    // ---- y = TK @ Xc + G @ Cc ----
    #pragma unroll
    for (int mt = 0; mt < 2; mt++)
        #pragma unroll
        for (int nt = 0; nt < 4; nt++) acc[mt][nt] = (f32x4)(0.f);
    {
        const unsigned short* sCc = (const unsigned short*)scratch;
        s16x8 a1[2], a2[2], bfx[4], bfc[4];
        #pragma unroll
        for (int mt = 0; mt < 2; mt++) {
            a1[mt] = *(const s16x8*)&sM[1280 + (mt * 16 + ml) * 40 + kg * 8];
            a2[mt] = *(const s16x8*)&sM[2560 + (mt * 16 + ml) * 40 + kg * 8];
        }
        #pragma unroll
        for (int nt = 0; nt < 4; nt++) {
            bfx[nt] = *(const s16x8*)&sXc[(w * 64 + nt * 16 + ml) * 40 + kg * 8];
            bfc[nt] = *(const s16x8*)&sCc[(w * 64 + nt * 16 + ml) * 40 + kg * 8];
        }
        #pragma unroll
        for (int mt = 0; mt < 2; mt++)
            #pragma unroll
            for (int nt = 0; nt < 4; nt++) {
                acc[mt][nt] = __builtin_amdgcn_mfma_f32_16x16x32_bf16(a1[mt], bfx[nt], acc[mt][nt], 0, 0, 0);
                acc[mt][nt] = __builtin_amdgcn_mfma_f32_16x16x32_bf16(a2[mt], bfc[nt], acc[mt][nt], 0, 0, 0);
            }
    }
    __syncthreads();
    #pragma unroll
    for (int mt = 0; mt < 2; mt++)
        #pragma unroll
        for (int nt = 0; nt < 4; nt++)
            #pragma unroll
            for (int r = 0; r < 4; r++)
                scratch[(mt * 16 + kg * 4 + r) * 260 + (w * 64 + nt * 16 + ml)] = acc[mt][nt][r];
    __syncthreads();
    const float Dh = Dp[h];
    u16x8* yp = (u16x8*)(yout + ((size_t)bh << 13) + (tid << 5));
    #pragma unroll
    for (int g = 0; g < 4; g++) {
        u16x8 pk;
        #pragma unroll
        for (int e = 0; e < 8; e++) {
            int i = g * 8 + e;
            pk[e] = f2bf(fmaf(Dh, xr[i], scratch[i * 260 + tid]));
        }
        yp[g] = pk;
    }
}

// ============ kernel 3: transpose y[bh][g] -> yT[b][g][h] ============
__global__ __launch_bounds__(256) void ytrans(const unsigned short* __restrict__ y,
                                              unsigned short* __restrict__ yT)
{
    __shared__ unsigned short sT[128 * 72];
    const int b = blockIdx.y, g0 = blockIdx.x << 6;
    const int tid = threadIdx.x;
    #pragma unroll
    for (int j = 0; j < 4; j++) {
        int li = tid + (j << 8);
        int h = li >> 3, g8 = (li & 7) << 3;
        u16x8 v = *(const u16x8*)(y + (((size_t)(b * 128 + h)) << 13) + g0 + g8);
        int gp = (g8 + (((h >> 3) & 7) << 3)) & 63;
        *(u16x8*)&sT[h * 72 + gp] = v;
    }
    __syncthreads();
    #pragma unroll
    for (int j = 0; j < 4; j++) {
        int li = tid + (j << 8);
        int g = li >> 4, h8 = (li & 15) << 3;
        u16x8 o;
        #pragma unroll
        for (int e = 0; e < 8; e++) {
            int h = h8 + e;
            int gp = (g + (((h >> 3) & 7) << 3)) & 63;
            o[e] = sT[h * 72 + gp];
        }
        *(u16x8*)(yT + (((size_t)(b * 8192 + g0 + g)) << 7) + h8) = o;
    }
}

// ============ kernel 4: MFMA dilated conv + bias + LeakyReLU + fused BN sums ============
__global__ __launch_bounds__(256) void conv_mfma(
    const unsigned short* __restrict__ yT,
    const unsigned short* __restrict__ WB,
    const float* __restrict__ b1, const float* __restrict__ b2,
    const float* __restrict__ b3, const float* __restrict__ b4,
    unsigned short* __restrict__ z, float* __restrict__ stats)
{
    __shared__ unsigned short sY[128 * 40];
    const int tid = threadIdx.x;
    const int lane = tid & 63, w = tid >> 6;
    const int branch = blockIdx.z, b = blockIdx.y;
    const int t0 = blockIdx.x << 7;
    const int d = 1 << branch;
    const int coH = (w & 1) << 6, tH = (w >> 1) << 6;
    const int ml = lane & 15, kg = lane >> 4;

    f32x4 acc[4][4];
    #pragma unroll
    for (int mt = 0; mt < 4; mt++)
        #pragma unroll
        for (int nt = 0; nt < 4; nt++) acc[mt][nt] = (f32x4)(0.f);

    const unsigned short* WBb = WB + (size_t)branch * 49152;

    for (int kc = 0; kc < 12; kc++) {
        const int tap = kc >> 2;
        const int hc = (kc & 3) << 5;
        const int goff = d * (tap - 1);
        // A-fragments straight from global (L2-resident weights)
        s16x8 af[4];
        #pragma unroll
        for (int mt = 0; mt < 4; mt++)
            af[mt] = *(const s16x8*)(WBb + (size_t)(coH + mt * 16 + ml) * 384 + (kc << 5) + (kg << 3));
        __syncthreads();
        #pragma unroll
        for (int j = 0; j < 2; j++) {
            int li = tid + (j << 8);
            int n = li >> 2, kq = (li & 3) << 3;
            int g = ((t0 + n) << 2) + goff;
            u16x8 v;
            if ((unsigned)g < 8192u) {
                v = *(const u16x8*)(yT + (((size_t)(b * 8192 + g)) << 7) + hc + kq);
            } else {
                #pragma unroll
                for (int e = 0; e < 8; e++) v[e] = 0;
            }
            *(u16x8*)&sY[n * 40 + kq] = v;
        }
        __syncthreads();
        s16x8 bfr[4];
        #pragma unroll
        for (int nt = 0; nt < 4; nt++)
            bfr[nt] = *(const s16x8*)&sY[(tH + nt * 16 + ml) * 40 + (kg << 3)];
        #pragma unroll
        for (int mt = 0; mt < 4; mt++)
            #pragma unroll
            for (int nt = 0; nt < 4; nt++)
                acc[mt][nt] = __builtin_amdgcn_mfma_f32_16x16x32_bf16(af[mt], bfr[nt], acc[mt][nt], 0, 0, 0);
    }

    const float* bp = (branch == 0) ? b1 : (branch == 1) ? b2 : (branch == 2) ? b3 : b4;
    #pragma unroll
    for (int mt = 0; mt < 4; mt++) {
        #pragma unroll
        for (int r = 0; r < 4; r++) {
            const int co = coH + mt * 16 + (kg << 2) + r;
            const float bb = bp[co];
            float s1 = 0.f, s2 = 0.f;
            #pragma unroll
            for (int nt = 0; nt < 4; nt++) {
                const int t = t0 + tH + nt * 16 + ml;
                float v = acc[mt][nt][r] + bb;
                if (branch != 0) v = (v >= 0.f) ? v : 0.3f * v;
                s1 += v;
                s2 = fmaf(v, v, s2);
                z[(((size_t)((branch * 16 + b) * 128 + co)) << 11) + t] = f2bf(v);
            }
            #pragma unroll
            for (int o = 8; o > 0; o >>= 1) {
                s1 += __shfl_down(s1, o, 16);
                s2 += __shfl_down(s2, o, 16);
            }
            if (ml == 0) {
                const int bc = branch * 128 + co;
                atomicAdd(&stats[bc * 2], s1);
                atomicAdd(&stats[bc * 2 + 1], s2);
            }
        }
    }
}

// ============ kernel 5: BN affine apply from raw sums (fp32 out) ============
__global__ __launch_bounds__(256) void bn_apply(const unsigned short* __restrict__ z,
                                                const float* __restrict__ stats,
                                                const float* __restrict__ gam,
                                                const float* __restrict__ bet,
                                                float* __restrict__ out)
{
    const size_t idx = (((size_t)blockIdx.x << 8) + threadIdx.x) << 3;
    const int t = (int)(idx & 2047);
    const size_t bc = idx >> 11;
    const int ch = (int)(bc & 511);
    const int b = (int)(bc >> 9);
    const int branch = ch >> 7, co = ch & 127;
    const float s1 = stats[ch * 2], s2 = stats[ch * 2 + 1];
    const float m = s1 * (1.0f / 32768.0f);
    const float var = fmaf(-m, m, s2 * (1.0f / 32768.0f));
    const float inv = rsqrtf(var + 1e-5f);
    const float ga = gam[co], be = bet[co];
    const float sc = ga * inv, sh = fmaf(-m, sc, be);
    const unsigned short* zp = z + (((size_t)((branch * 16 + b) * 128 + co)) << 11) + t;
    u16x8 v = *(const u16x8*)zp;
    float4 o0, o1;
    o0.x = fmaf(bf2f(v[0]), sc, sh); o0.y = fmaf(bf2f(v[1]), sc, sh);
    o0.z = fmaf(bf2f(v[2]), sc, sh); o0.w = fmaf(bf2f(v[3]), sc, sh);
    o1.x = fmaf(bf2f(v[4]), sc, sh); o1.y = fmaf(bf2f(v[5]), sc, sh);
    o1.z = fmaf(bf2f(v[6]), sc, sh); o1.w = fmaf(bf2f(v[7]), sc, sh);
    *(float4*)(out + idx)     = o0;
    *(float4*)(out + idx + 4) = o1;
}

extern "C" void kernel_launch(void* const* d_in, const int* in_sizes, int n_in,
                              void* d_out, int out_size, void* d_ws, size_t ws_size,
                              hipStream_t stream) {
    const float* x      = (const float*)d_in[0];
    const float* log_dt = (const float*)d_in[1];
    const float* A_log  = (const float*)d_in[2];
    const float* A_imag = (const float*)d_in[3];
    const float* B_re   = (const float*)d_in[4];
    const float* B_im   = (const float*)d_in[5];
    const float* C_re   = (const float*)d_in[6];
    const float* C_im   = (const float*)d_in[7];
    const float* Dp     = (const float*)d_in[8];
    const float* w1 = (const float*)d_in[9];
    const float* b1 = (const float*)d_in[10];
    const float* w2 = (const float*)d_in[11];
    const float* b2 = (const float*)d_in[12];
    const float* w3 = (const float*)d_in[13];
    const float* b3 = (const float*)d_in[14];
    const float* w4 = (const float*)d_in[15];
    const float* b4 = (const float*)d_in[16];
    const float* gam = (const float*)d_in[17];
    const float* bet = (const float*)d_in[18];

    float* w32p = (float*)d_ws;
    unsigned short* MATSp = (unsigned short*)((char*)d_ws + MATS_OFF);
    unsigned short* WBp = (unsigned short*)((char*)d_ws + WB_OFF);
    float* stats = (float*)((char*)d_ws + STAT_OFF);
    unsigned short* yws = (unsigned short*)((char*)d_ws + Y_OFF);
    unsigned short* yT  = (unsigned short*)((char*)d_ws + YT_OFF);
    unsigned short* zws = (unsigned short*)((char*)d_ws + Z_OFF);
    float* out = (float*)d_out;

    precompute_s4d<<<dim3(128), dim3(256), 0, stream>>>(log_dt, A_log, A_imag,
                                                        B_re, B_im, C_re, C_im, w32p, MATSp);
    wpack<<<dim3(768), dim3(256), 0, stream>>>(w1, w2, w3, w4, WBp);
    stats_zero<<<dim3(1), dim3(256), 0, stream>>>(stats);
    s4d_mfma<<<dim3(2048), dim3(256), 0, stream>>>(x, w32p, MATSp, Dp, yws);
    ytrans<<<dim3(128, 16), dim3(256), 0, stream>>>(yws, yT);
    conv_mfma<<<dim3(16, 16, 4), dim3(256), 0, stream>>>(yT, WBp, b1, b2, b3, b4, zws, stats);
    bn_apply<<<dim3(8192), dim3(256), 0, stream>>>(zws, stats, gam, bet, out);
}

// Round 6
// 279.906 us; speedup vs baseline: 1.7312x; 1.7312x over previous
//
#include <hip/hip_runtime.h>
#include <math.h>

typedef unsigned short u16x8 __attribute__((ext_vector_type(8)));
typedef unsigned short u16x2 __attribute__((ext_vector_type(2)));
typedef short s16x8 __attribute__((ext_vector_type(8)));
typedef float f32x4 __attribute__((ext_vector_type(4)));

__device__ __forceinline__ float bf2f(unsigned short u) {
    union { unsigned int i; float f; } v; v.i = ((unsigned int)u) << 16; return v.f;
}
__device__ __forceinline__ unsigned short f2bf(float f) {
    union { unsigned int i; float f; } v; v.f = f;
    unsigned int r = v.i + 0x7FFFu + ((v.i >> 16) & 1u);
    return (unsigned short)(r >> 16);
}

// ---------------- workspace layout (bytes) ----------------
#define MATS_OFF 16384
#define WB_OFF   548864
#define STAT_OFF 942080
#define Y_OFF    1048576
#define YT_OFF   34603008
#define Z_OFF    Y_OFF

// ============ kernel 1: S4D matrix precompute (double precision) ============
__global__ void precompute_s4d(const float* __restrict__ log_dt,
                               const float* __restrict__ A_log,
                               const float* __restrict__ A_imag,
                               const float* __restrict__ B_re,
                               const float* __restrict__ B_im,
                               const float* __restrict__ C_re,
                               const float* __restrict__ C_im,
                               float* __restrict__ w32,
                               unsigned short* __restrict__ MATS)
{
    const int h = blockIdx.x;
    const int tid = threadIdx.x;
    const double dt = exp((double)log_dt[h]);

    #pragma unroll 1
    for (int it = 0; it < 4; it++) {
        int idx = tid + (it << 8);
        int s = idx >> 5, i = idx & 31;
        int n = s >> 1;
        double Ar = -exp((double)A_log[h * 16 + n]);
        double Ai = (double)A_imag[h * 16 + n];
        double dr = dt * Ar, di = dt * Ai;
        double l = (double)(31 - i);
        double e = exp(l * dr);
        double val = (s & 1) ? e * sin(l * di) : e * cos(l * di);
        MATS[(size_t)h * 2080 + s * 32 + i] = f2bf((float)val);
    }
    #pragma unroll 1
    for (int it = 0; it < 4; it++) {
        int idx = tid + (it << 8);
        int j = idx >> 5, s = idx & 31;
        int n = s >> 1;
        double Ar = -exp((double)A_log[h * 16 + n]);
        double Ai = (double)A_imag[h * 16 + n];
        double dr = dt * Ar, di = dt * Ai;
        double ew = exp(dr);
        double wr = ew * cos(di), wi = ew * sin(di);
        double nr = wr - 1.0, ni = wi;
        double inv = 1.0 / (Ar * Ar + Ai * Ai);
        double tr = (nr * Ar + ni * Ai) * inv;
        double ti = (ni * Ar - nr * Ai) * inv;
        double Br = (double)B_re[h * 16 + n], Bi = (double)B_im[h * 16 + n];
        double dbr = tr * Br - ti * Bi, dbi = tr * Bi + ti * Br;
        double Cr = (double)C_re[h * 16 + n], Ci = (double)C_im[h * 16 + n];
        double cbr = Cr * dbr - Ci * dbi, cbi = Cr * dbi + Ci * dbr;
        double m = (double)(j + 1);
        double e = exp(m * dr);
        double pr = e * cos(m * di), pi = e * sin(m * di);
        double gr = cbr * pr - cbi * pi, gi = cbr * pi + cbi * pr;
        double val = (s & 1) ? -2.0 * gi : 2.0 * gr;
        MATS[(size_t)h * 2080 + 1024 + j * 32 + s] = f2bf((float)val);
    }
    {
        int l = tid >> 3, sub = tid & 7;
        double accd = 0.0;
        #pragma unroll 1
        for (int q = 0; q < 2; q++) {
            int n = sub * 2 + q;
            double Ar = -exp((double)A_log[h * 16 + n]);
            double Ai = (double)A_imag[h * 16 + n];
            double dr = dt * Ar, di = dt * Ai;
            double ew = exp(dr);
            double wr = ew * cos(di), wi = ew * sin(di);
            double nr = wr - 1.0, ni = wi;
            double inv = 1.0 / (Ar * Ar + Ai * Ai);
            double tr = (nr * Ar + ni * Ai) * inv;
            double ti = (ni * Ar - nr * Ai) * inv;
            double Br = (double)B_re[h * 16 + n], Bi = (double)B_im[h * 16 + n];
            double dbr = tr * Br - ti * Bi, dbi = tr * Bi + ti * Br;
            double Cr = (double)C_re[h * 16 + n], Ci = (double)C_im[h * 16 + n];
            double cbr = Cr * dbr - Ci * dbi, cbi = Cr * dbi + Ci * dbr;
            double l2 = (double)l;
            double e = exp(l2 * dr);
            double wlr = e * cos(l2 * di), wli = e * sin(l2 * di);
            accd += cbr * wlr - cbi * wli;
        }
        float accf = (float)(2.0 * accd);
        #pragma unroll
        for (int o = 4; o > 0; o >>= 1) accf += __shfl_down(accf, o, 8);
        if (sub == 0) MATS[(size_t)h * 2080 + 2048 + l] = f2bf(accf);
    }
    if (tid < 16) {
        int n = tid;
        double Ar = -exp((double)A_log[h * 16 + n]);
        double Ai = (double)A_imag[h * 16 + n];
        double dr = dt * Ar, di = dt * Ai;
        double e = exp(32.0 * dr);
        w32[h * 32 + 2 * n]     = (float)(e * cos(32.0 * di));
        w32[h * 32 + 2 * n + 1] = (float)(e * sin(32.0 * di));
    }
}

// ============ kernel 1b: pack conv weights to bf16 ============
__global__ void wpack(const float* __restrict__ w1, const float* __restrict__ w2,
                      const float* __restrict__ w3, const float* __restrict__ w4,
                      unsigned short* __restrict__ WB)
{
    int idx = blockIdx.x * 256 + threadIdx.x;
    int br = idx / 49152;
    int r  = idx - br * 49152;
    int co = r / 384;
    int k  = r - co * 384;
    int tap = k >> 7, h = k & 127;
    const float* wp = (br == 0) ? w1 : (br == 1) ? w2 : (br == 2) ? w3 : w4;
    WB[idx] = f2bf(wp[co * 384 + h * 3 + tap]);
}

// ============ kernel 2: S4D — MFMA chunk matmuls + shuffle carry scan ============
__global__ __launch_bounds__(256, 2) void s4d_mfma(const float* __restrict__ x,
                                                   const float* __restrict__ w32,
                                                   const unsigned short* __restrict__ MATS,
                                                   const float* __restrict__ Dp,
                                                   unsigned short* __restrict__ yout)
{
    __shared__ unsigned short sXc[256 * 40];
    __shared__ unsigned short sM[3840];        // V @0, TK @1280, G @2560 (stride 40)
    __shared__ float spow2[256];               // w32^(2^k), k=0..7
    __shared__ unsigned short skr[32];
    __shared__ float swc[128];                 // cross-wave carries 4x32
    __shared__ float scratch[8320];            // 32 x 260 unpack buffer / sCc u16
    const int tid = threadIdx.x;
    const int bh = blockIdx.x;
    const int h = bh & 127;
    const int lane = tid & 63, w = tid >> 6;
    const int ml = lane & 15, kg = lane >> 4;

    float xr[32];
    const float4* xp4 = (const float4*)(x + ((size_t)bh << 13) + (tid << 5));
    #pragma unroll
    for (int i = 0; i < 8; i++) {
        float4 v = xp4[i];
        xr[4 * i] = v.x; xr[4 * i + 1] = v.y; xr[4 * i + 2] = v.z; xr[4 * i + 3] = v.w;
    }
    #pragma unroll
    for (int g = 0; g < 4; g++) {
        u16x8 pk;
        #pragma unroll
        for (int e = 0; e < 8; e++) pk[e] = f2bf(xr[g * 8 + e]);
        *(u16x8*)&sXc[tid * 40 + g * 8] = pk;
    }
    {
        int matv = tid >> 7, r = (tid >> 2) & 31, sg = tid & 3;
        u16x8 v = *(const u16x8*)(MATS + (size_t)h * 2080 + matv * 1024 + r * 32 + sg * 8);
        *(u16x8*)&sM[matv * 2560 + r * 40 + sg * 8] = v;
    }
    if (tid < 4) {
        u16x8 v = *(const u16x8*)(MATS + (size_t)h * 2080 + 2048 + tid * 8);
        *(u16x8*)&skr[tid * 8] = v;
    }
    if (tid < 16) {
        float rr = w32[h * 32 + 2 * tid], ii = w32[h * 32 + 2 * tid + 1];
        #pragma unroll
        for (int k = 0; k < 8; k++) {
            spow2[k * 32 + 2 * tid] = rr; spow2[k * 32 + 2 * tid + 1] = ii;
            float n2r = rr * rr - ii * ii, n2i = 2.f * rr * ii;
            rr = n2r; ii = n2i;
        }
    }
    __syncthreads();
    #pragma unroll
    for (int it = 0; it < 4; it++) {
        int idx = tid + (it << 8);
        int j = idx >> 5, i = idx & 31;
        sM[1280 + j * 40 + i] = (i <= j) ? skr[j - i] : (unsigned short)0;
    }
    __syncthreads();

    // ---- E = V @ Xc ----
    f32x4 acc[2][4];
    #pragma unroll
    for (int mt = 0; mt < 2; mt++)
        #pragma unroll
        for (int nt = 0; nt < 4; nt++) acc[mt][nt] = (f32x4)(0.f);
    {
        s16x8 af[2], bfr[4];
        #pragma unroll
        for (int mt = 0; mt < 2; mt++)
            af[mt] = *(const s16x8*)&sM[(mt * 16 + ml) * 40 + kg * 8];
        #pragma unroll
        for (int nt = 0; nt < 4; nt++)
            bfr[nt] = *(const s16x8*)&sXc[(w * 64 + nt * 16 + ml) * 40 + kg * 8];
        #pragma unroll
        for (int mt = 0; mt < 2; mt++)
            #pragma unroll
            for (int nt = 0; nt < 4; nt++)
                acc[mt][nt] = __builtin_amdgcn_mfma_f32_16x16x32_bf16(af[mt], bfr[nt], acc[mt][nt], 0, 0, 0);
    }
    #pragma unroll
    for (int mt = 0; mt < 2; mt++)
        #pragma unroll
        for (int nt = 0; nt < 4; nt++)
            #pragma unroll
            for (int r = 0; r < 4; r++)
                scratch[(mt * 16 + kg * 4 + r) * 260 + (w * 64 + nt * 16 + ml)] = acc[mt][nt][r];
    __syncthreads();
    float zr[16], zi[16];
    #pragma unroll
    for (int n = 0; n < 16; n++) {
        zr[n] = scratch[(2 * n) * 260 + tid];
        zi[n] = scratch[(2 * n + 1) * 260 + tid];
    }

    // ---- in-wave inclusive scan (shuffles) ----
    #pragma unroll 1
    for (int k = 0; k < 6; k++) {
        const int o = 1 << k;
        const bool act = lane >= o;
        #pragma unroll
        for (int n = 0; n < 16; n++) {
            float lr = __shfl(zr[n], lane - o);
            float li = __shfl(zi[n], lane - o);
            float mr = spow2[(k << 5) + 2 * n], mi = spow2[(k << 5) + 2 * n + 1];
            float nzr = fmaf(mr, lr, fmaf(-mi, li, zr[n]));
            float nzi = fmaf(mr, li, fmaf(mi, lr, zi[n]));
            zr[n] = act ? nzr : zr[n];
            zi[n] = act ? nzi : zi[n];
        }
    }
    if (lane == 63) {
        #pragma unroll
        for (int n = 0; n < 16; n++) {
            swc[w * 32 + 2 * n]     = zr[n];
            swc[w * 32 + 2 * n + 1] = zi[n];
        }
    }
    __syncthreads();
    float qr[16], qi[16];
    #pragma unroll
    for (int n = 0; n < 16; n++) { qr[n] = 0.f; qi[n] = 0.f; }
    #pragma unroll 1
    for (int a = 0; a < 3; a++) {
        if (a < w) {
            int p = w - 1 - a;
            #pragma unroll
            for (int n = 0; n < 16; n++) {
                float ar = swc[a * 32 + 2 * n], ai = swc[a * 32 + 2 * n + 1];
                float mr = 1.f, mi = 0.f;
                if (p > 0) { mr = spow2[((5 + p) << 5) + 2 * n]; mi = spow2[((5 + p) << 5) + 2 * n + 1]; }
                qr[n] = fmaf(mr, ar, fmaf(-mi, ai, qr[n]));
                qi[n] = fmaf(mr, ai, fmaf(mi, ar, qi[n]));
            }
        }
    }
    float pjr[16], pji[16];
    #pragma unroll
    for (int n = 0; n < 16; n++) { pjr[n] = 1.f; pji[n] = 0.f; }
    #pragma unroll 1
    for (int k = 0; k < 6; k++) {
        const bool bit = (lane >> k) & 1;
        #pragma unroll
        for (int n = 0; n < 16; n++) {
            float mr = spow2[(k << 5) + 2 * n], mi = spow2[(k << 5) + 2 * n + 1];
            float nr2 = pjr[n] * mr - pji[n] * mi;
            float ni2 = fmaf(pjr[n], mi, pji[n] * mr);
            pjr[n] = bit ? nr2 : pjr[n];
            pji[n] = bit ? ni2 : pji[n];
        }
    }
    #pragma unroll
    for (int n = 0; n < 16; n++) {
        float pr = __shfl(zr[n], lane - 1);
        float pi = __shfl(zi[n], lane - 1);
        pr = (lane == 0) ? 0.f : pr;
        pi = (lane == 0) ? 0.f : pi;
        zr[n] = fmaf(pjr[n], qr[n], fmaf(-pji[n], qi[n], pr));
        zi[n] = fmaf(pjr[n], qi[n], fmaf(pji[n], qr[n], pi));
    }
    {
        unsigned short* sCc = (unsigned short*)scratch;
        #pragma unroll
        for (int g = 0; g < 4; g++) {
            u16x8 pk;
            #pragma unroll
            for (int q = 0; q < 4; q++) {
                pk[2 * q]     = f2bf(zr[g * 4 + q]);
                pk[2 * q + 1] = f2bf(zi[g * 4 + q]);
            }
            *(u16x8*)&sCc[tid * 40 + g * 8] = pk;
        }
    }
    __syncthreads();

    // ---- y = TK @ Xc + G @ Cc ----
    #pragma unroll
    for (int mt = 0; mt < 2; mt++)
        #pragma unroll
        for (int nt = 0; nt < 4; nt++) acc[mt][nt] = (f32x4)(0.f);
    {
        const unsigned short* sCc = (const unsigned short*)scratch;
        s16x8 a1[2], a2[2], bfx[4], bfc[4];
        #pragma unroll
        for (int mt = 0; mt < 2; mt++) {
            a1[mt] = *(const s16x8*)&sM[1280 + (mt * 16 + ml) * 40 + kg * 8];
            a2[mt] = *(const s16x8*)&sM[2560 + (mt * 16 + ml) * 40 + kg * 8];
        }
        #pragma unroll
        for (int nt = 0; nt < 4; nt++) {
            bfx[nt] = *(const s16x8*)&sXc[(w * 64 + nt * 16 + ml) * 40 + kg * 8];
            bfc[nt] = *(const s16x8*)&sCc[(w * 64 + nt * 16 + ml) * 40 + kg * 8];
        }
        #pragma unroll
        for (int mt = 0; mt < 2; mt++)
            #pragma unroll
            for (int nt = 0; nt < 4; nt++) {
                acc[mt][nt] = __builtin_amdgcn_mfma_f32_16x16x32_bf16(a1[mt], bfx[nt], acc[mt][nt], 0, 0, 0);
                acc[mt][nt] = __builtin_amdgcn_mfma_f32_16x16x32_bf16(a2[mt], bfc[nt], acc[mt][nt], 0, 0, 0);
            }
    }
    __syncthreads();
    #pragma unroll
    for (int mt = 0; mt < 2; mt++)
        #pragma unroll
        for (int nt = 0; nt < 4; nt++)
            #pragma unroll
            for (int r = 0; r < 4; r++)
                scratch[(mt * 16 + kg * 4 + r) * 260 + (w * 64 + nt * 16 + ml)] = acc[mt][nt][r];
    __syncthreads();
    const float Dh = Dp[h];
    u16x8* yp = (u16x8*)(yout + ((size_t)bh << 13) + (tid << 5));
    #pragma unroll
    for (int g = 0; g < 4; g++) {
        u16x8 pk;
        #pragma unroll
        for (int e = 0; e < 8; e++) {
            int i = g * 8 + e;
            pk[e] = f2bf(fmaf(Dh, xr[i], scratch[i * 260 + tid]));
        }
        yp[g] = pk;
    }
}

// ============ kernel 3: transpose y[bh][g] -> yT[b][g][h] ============
__global__ __launch_bounds__(256) void ytrans(const unsigned short* __restrict__ y,
                                              unsigned short* __restrict__ yT)
{
    __shared__ unsigned short sT[128 * 72];
    const int b = blockIdx.y, g0 = blockIdx.x << 6;
    const int tid = threadIdx.x;
    #pragma unroll
    for (int j = 0; j < 4; j++) {
        int li = tid + (j << 8);
        int h = li >> 3, g8 = (li & 7) << 3;
        u16x8 v = *(const u16x8*)(y + (((size_t)(b * 128 + h)) << 13) + g0 + g8);
        int gp = (g8 + (((h >> 3) & 7) << 3)) & 63;
        *(u16x8*)&sT[h * 72 + gp] = v;
    }
    __syncthreads();
    #pragma unroll
    for (int j = 0; j < 4; j++) {
        int li = tid + (j << 8);
        int g = li >> 4, h8 = (li & 15) << 3;
        u16x8 o;
        #pragma unroll
        for (int e = 0; e < 8; e++) {
            int h = h8 + e;
            int gp = (g + (((h >> 3) & 7) << 3)) & 63;
            o[e] = sT[h * 72 + gp];
        }
        *(u16x8*)(yT + (((size_t)(b * 8192 + g0 + g)) << 7) + h8) = o;
    }
}

// ============ kernel 4: MFMA dilated conv + bias + LeakyReLU (round-3 proven) ============
// grid (16 ttile, 4 branch, 16 b) — consecutive blocks share one b's yT slice.
__global__ __launch_bounds__(256) void conv_mfma(
    const unsigned short* __restrict__ yT,
    const unsigned short* __restrict__ WB,
    const float* __restrict__ b1, const float* __restrict__ b2,
    const float* __restrict__ b3, const float* __restrict__ b4,
    unsigned short* __restrict__ z)
{
    __shared__ unsigned short sW[128 * 40];
    __shared__ unsigned short sY[128 * 40];
    const int tid = threadIdx.x;
    const int lane = tid & 63, w = tid >> 6;
    const int branch = blockIdx.y, b = blockIdx.z;
    const int t0 = blockIdx.x << 7;
    const int d = 1 << branch;
    const int coH = (w & 1) << 6, tH = (w >> 1) << 6;
    const int ml = lane & 15, kg = lane >> 4;

    f32x4 acc[4][4];
    #pragma unroll
    for (int mt = 0; mt < 4; mt++)
        #pragma unroll
        for (int nt = 0; nt < 4; nt++) acc[mt][nt] = (f32x4)(0.f);

    const unsigned short* WBb = WB + (size_t)branch * 49152;

    for (int kc = 0; kc < 12; kc++) {
        const int tap = kc >> 2, hc = (kc & 3) << 5;
        const int goff = d * (tap - 1);
        __syncthreads();
        #pragma unroll
        for (int j = 0; j < 2; j++) {
            int li = tid + (j << 8);
            int co = li >> 2, kq = (li & 3) << 3;
            u16x8 v = *(const u16x8*)(WBb + (size_t)co * 384 + (kc << 5) + kq);
            *(u16x8*)&sW[co * 40 + kq] = v;
        }
        #pragma unroll
        for (int j = 0; j < 2; j++) {
            int li = tid + (j << 8);
            int n = li >> 2, kq = (li & 3) << 3;
            int g = ((t0 + n) << 2) + goff;
            u16x8 v;
            if ((unsigned)g < 8192u) {
                v = *(const u16x8*)(yT + (((size_t)(b * 8192 + g)) << 7) + hc + kq);
            } else {
                #pragma unroll
                for (int e = 0; e < 8; e++) v[e] = 0;
            }
            *(u16x8*)&sY[n * 40 + kq] = v;
        }
        __syncthreads();
        s16x8 af[4], bfr[4];
        #pragma unroll
        for (int mt = 0; mt < 4; mt++)
            af[mt] = *(const s16x8*)&sW[(coH + mt * 16 + ml) * 40 + (kg << 3)];
        #pragma unroll
        for (int nt = 0; nt < 4; nt++)
            bfr[nt] = *(const s16x8*)&sY[(tH + nt * 16 + ml) * 40 + (kg << 3)];
        #pragma unroll
        for (int mt = 0; mt < 4; mt++)
            #pragma unroll
            for (int nt = 0; nt < 4; nt++)
                acc[mt][nt] = __builtin_amdgcn_mfma_f32_16x16x32_bf16(af[mt], bfr[nt], acc[mt][nt], 0, 0, 0);
    }

    const float* bp = (branch == 0) ? b1 : (branch == 1) ? b2 : (branch == 2) ? b3 : b4;
    #pragma unroll
    for (int mt = 0; mt < 4; mt++) {
        #pragma unroll
        for (int r = 0; r < 4; r++) {
            const int co = coH + mt * 16 + (kg << 2) + r;
            const float bb = bp[co];
            #pragma unroll
            for (int nt = 0; nt < 4; nt++) {
                const int t = t0 + tH + nt * 16 + ml;
                float v = acc[mt][nt][r] + bb;
                if (branch != 0) v = (v >= 0.f) ? v : 0.3f * v;
                z[(((size_t)((branch * 16 + b) * 128 + co)) << 11) + t] = f2bf(v);
            }
        }
    }
}

// ============ kernel 5: BN batch stats ============
__global__ __launch_bounds__(256) void bn_stats(const unsigned short* __restrict__ z,
                                                float* __restrict__ stats)
{
    const int bc = blockIdx.x;
    const int branch = bc >> 7, co = bc & 127;
    const int tid = threadIdx.x;
    float s1 = 0.f, s2 = 0.f;
    for (int i = tid; i < 16384; i += 256) {
        int b = i >> 10, tp = (i & 1023) << 1;
        const unsigned short* p = z + (((size_t)((branch * 16 + b) * 128 + co)) << 11) + tp;
        u16x2 v2 = *(const u16x2*)p;
        float a = bf2f(v2[0]), c = bf2f(v2[1]);
        s1 += a + c;
        s2 = fmaf(a, a, fmaf(c, c, s2));
    }
    #pragma unroll
    for (int o = 32; o > 0; o >>= 1) { s1 += __shfl_down(s1, o); s2 += __shfl_down(s2, o); }
    __shared__ float r1[4], r2[4];
    const int lane = tid & 63, wid = tid >> 6;
    if (lane == 0) { r1[wid] = s1; r2[wid] = s2; }
    __syncthreads();
    if (tid == 0) {
        float t1 = r1[0] + r1[1] + r1[2] + r1[3];
        float t2 = r2[0] + r2[1] + r2[2] + r2[3];
        float m = t1 * (1.0f / 32768.0f);
        float var = t2 * (1.0f / 32768.0f) - m * m;
        stats[bc * 2]     = m;
        stats[bc * 2 + 1] = 1.0f / sqrtf(var + 1e-5f);
    }
}

// ============ kernel 6: BN affine apply (fp32 out) ============
__global__ __launch_bounds__(256) void bn_apply(const unsigned short* __restrict__ z,
                                                const float* __restrict__ stats,
                                                const float* __restrict__ gam,
                                                const float* __restrict__ bet,
                                                float* __restrict__ out)
{
    const size_t idx = (((size_t)blockIdx.x << 8) + threadIdx.x) << 3;
    const int t = (int)(idx & 2047);
    const size_t bc = idx >> 11;
    const int ch = (int)(bc & 511);
    const int b = (int)(bc >> 9);
    const int branch = ch >> 7, co = ch & 127;
    const float m = stats[ch * 2], inv = stats[ch * 2 + 1];
    const float ga = gam[co], be = bet[co];
    const float sc = ga * inv, sh = fmaf(-m, sc, be);
    const unsigned short* zp = z + (((size_t)((branch * 16 + b) * 128 + co)) << 11) + t;
    u16x8 v = *(const u16x8*)zp;
    float4 o0, o1;
    o0.x = fmaf(bf2f(v[0]), sc, sh); o0.y = fmaf(bf2f(v[1]), sc, sh);
    o0.z = fmaf(bf2f(v[2]), sc, sh); o0.w = fmaf(bf2f(v[3]), sc, sh);
    o1.x = fmaf(bf2f(v[4]), sc, sh); o1.y = fmaf(bf2f(v[5]), sc, sh);
    o1.z = fmaf(bf2f(v[6]), sc, sh); o1.w = fmaf(bf2f(v[7]), sc, sh);
    *(float4*)(out + idx)     = o0;
    *(float4*)(out + idx + 4) = o1;
}

extern "C" void kernel_launch(void* const* d_in, const int* in_sizes, int n_in,
                              void* d_out, int out_size, void* d_ws, size_t ws_size,
                              hipStream_t stream) {
    const float* x      = (const float*)d_in[0];
    const float* log_dt = (const float*)d_in[1];
    const float* A_log  = (const float*)d_in[2];
    const float* A_imag = (const float*)d_in[3];
    const float* B_re   = (const float*)d_in[4];
    const float* B_im   = (const float*)d_in[5];
    const float* C_re   = (const float*)d_in[6];
    const float* C_im   = (const float*)d_in[7];
    const float* Dp     = (const float*)d_in[8];
    const float* w1 = (const float*)d_in[9];
    const float* b1 = (const float*)d_in[10];
    const float* w2 = (const float*)d_in[11];
    const float* b2 = (const float*)d_in[12];
    const float* w3 = (const float*)d_in[13];
    const float* b3 = (const float*)d_in[14];
    const float* w4 = (const float*)d_in[15];
    const float* b4 = (const float*)d_in[16];
    const float* gam = (const float*)d_in[17];
    const float* bet = (const float*)d_in[18];

    float* w32p = (float*)d_ws;
    unsigned short* MATSp = (unsigned short*)((char*)d_ws + MATS_OFF);
    unsigned short* WBp = (unsigned short*)((char*)d_ws + WB_OFF);
    float* stats = (float*)((char*)d_ws + STAT_OFF);
    unsigned short* yws = (unsigned short*)((char*)d_ws + Y_OFF);
    unsigned short* yT  = (unsigned short*)((char*)d_ws + YT_OFF);
    unsigned short* zws = (unsigned short*)((char*)d_ws + Z_OFF);
    float* out = (float*)d_out;

    precompute_s4d<<<dim3(128), dim3(256), 0, stream>>>(log_dt, A_log, A_imag,
                                                        B_re, B_im, C_re, C_im, w32p, MATSp);
    wpack<<<dim3(768), dim3(256), 0, stream>>>(w1, w2, w3, w4, WBp);
    s4d_mfma<<<dim3(2048), dim3(256), 0, stream>>>(x, w32p, MATSp, Dp, yws);
    ytrans<<<dim3(128, 16), dim3(256), 0, stream>>>(yws, yT);
    conv_mfma<<<dim3(16, 4, 16), dim3(256), 0, stream>>>(yT, WBp, b1, b2, b3, b4, zws);
    bn_stats<<<dim3(512), dim3(256), 0, stream>>>(zws, stats);
    bn_apply<<<dim3(8192), dim3(256), 0, stream>>>(zws, stats, gam, bet, out);
}